// Round 1
// baseline (389.108 us; speedup 1.0000x reference)
//
#include <hip/hip_runtime.h>
#include <hip/hip_bf16.h>

#define BATCH 8
#define SEQ 4096
#define EMB 1024
#define HEAD 64
#define N3 192   // 3*HEAD, layout: k [0,64) | q [64,128) | v [128,192)

#define QBLK 64
#define KVBLK 32
#define PSTR 40  // padded LDS row stride (ushorts) -> 80B, 16B aligned, breaks pow2 banks

typedef __attribute__((ext_vector_type(4))) float f32x4;
typedef __attribute__((ext_vector_type(8))) short bf16x8;
typedef __attribute__((ext_vector_type(4))) float float4v;

#define LOG2E 1.4426950408889634f

static __device__ __forceinline__ unsigned short f2bf(float f) {
  unsigned int x = __builtin_bit_cast(unsigned int, f);
  x += 0x7fffu + ((x >> 16) & 1u);   // round-to-nearest-even
  return (unsigned short)(x >> 16);
}

// --- Kernel 1: W [1024][192] f32 -> Wt [192][1024] bf16 (contiguous-K B-fragments) ---
__global__ __launch_bounds__(256) void wt_kernel(const float* __restrict__ W,
                                                 unsigned short* __restrict__ Wt) {
  int idx = blockIdx.x * 256 + threadIdx.x;   // grid sized exactly EMB*N3/256
  int k = idx / N3, c = idx % N3;
  Wt[(size_t)c * EMB + k] = f2bf(W[idx]);
}

// --- Kernel 2: kqv[32768][192] bf16 = x @ W, q-cols pre-scaled by 0.125 ---
__global__ __launch_bounds__(256) void qkv_kernel(const float* __restrict__ x,
                                                  const unsigned short* __restrict__ Wt,
                                                  unsigned short* __restrict__ kqv) {
  const int wid = threadIdx.x >> 6;
  const int lane = threadIdx.x & 63;
  const int l16 = lane & 15;   // A-row / B-col within 16
  const int lg = lane >> 4;    // k-group: k = lg*8 + j
  const int m0 = blockIdx.x * 64 + wid * 16;

  f32x4 acc[12];
#pragma unroll
  for (int t = 0; t < 12; ++t) acc[t] = (f32x4)0.0f;

  const float* xrow = x + (size_t)(m0 + l16) * EMB;
  for (int kc = 0; kc < EMB; kc += 32) {
    float4v a0 = *(const float4v*)(xrow + kc + lg * 8);
    float4v a1 = *(const float4v*)(xrow + kc + lg * 8 + 4);
    bf16x8 af;
#pragma unroll
    for (int j = 0; j < 4; ++j) {
      af[j] = (short)f2bf(a0[j]);
      af[4 + j] = (short)f2bf(a1[j]);
    }
#pragma unroll
    for (int t = 0; t < 12; ++t) {
      bf16x8 bfv = *(const bf16x8*)(Wt + (size_t)(t * 16 + l16) * EMB + kc + lg * 8);
      acc[t] = __builtin_amdgcn_mfma_f32_16x16x32_bf16(af, bfv, acc[t], 0, 0, 0);
    }
  }
  // D layout: col = l16, row = lg*4 + r
#pragma unroll
  for (int t = 0; t < 12; ++t) {
#pragma unroll
    for (int r = 0; r < 4; ++r) {
      int row = m0 + lg * 4 + r;
      int col = t * 16 + l16;
      float v = acc[t][r];
      if (col >= 64 && col < 128) v *= 0.125f;   // pre-scale q by 1/sqrt(64), exact in bf16
      kqv[(size_t)row * N3 + col] = f2bf(v);
    }
  }
}

// --- Kernel 3: causal flash attention, out fp32 [B][T][64] ---
__global__ __launch_bounds__(256) void attn_kernel(const unsigned short* __restrict__ kqv,
                                                   float* __restrict__ out) {
  __shared__ __align__(16) unsigned short V_lds[HEAD][PSTR];      // V transposed: [d][kv]
  __shared__ __align__(16) unsigned short P_lds[4][16][PSTR];     // per-wave P: [q][kv]

  const int tid = threadIdx.x;
  const int wid = tid >> 6;
  const int lane = tid & 63;
  const int l16 = lane & 15;
  const int lg = lane >> 4;

  const int b = blockIdx.x % BATCH;
  const int qt = (SEQ / QBLK - 1) - (blockIdx.x / BATCH);  // longest work first
  const int q0 = qt * QBLK;
  const unsigned short* base = kqv + (size_t)b * SEQ * N3;

  // Q fragments for this wave's 16 rows (q cols at offset 64, already scaled)
  const int qrow = q0 + wid * 16 + l16;
  bf16x8 qf0 = *(const bf16x8*)(base + (size_t)qrow * N3 + 64 + lg * 8);
  bf16x8 qf1 = *(const bf16x8*)(base + (size_t)qrow * N3 + 96 + lg * 8);

  f32x4 o0 = (f32x4)0.0f, o1 = (f32x4)0.0f, o2 = (f32x4)0.0f, o3 = (f32x4)0.0f;
  float m_[4], lsum[4];
#pragma unroll
  for (int r = 0; r < 4; ++r) { m_[r] = -3.0e38f; lsum[r] = 0.0f; }

  const int my_q = q0 + wid * 16 + lg * 4;   // + r gives this lane's 4 q rows
  const int kv_end = q0 + QBLK;

  for (int kv0 = 0; kv0 < kv_end; kv0 += KVBLK) {
    // stage V tile transposed into LDS (v cols at offset 128)
    {
      const int kv = tid >> 3;            // 0..31
      const int d8 = (tid & 7) * 8;       // 0,8,..,56
      bf16x8 v = *(const bf16x8*)(base + (size_t)(kv0 + kv) * N3 + 128 + d8);
#pragma unroll
      for (int j = 0; j < 8; ++j) V_lds[d8 + j][kv] = (unsigned short)v[j];
    }
    __syncthreads();

    // S = Q K^T  (two 16-col tiles)
    f32x4 s0 = (f32x4)0.0f, s1 = (f32x4)0.0f;
    {
      const unsigned short* k0p = base + (size_t)(kv0 + l16) * N3;
      const unsigned short* k1p = base + (size_t)(kv0 + 16 + l16) * N3;
      bf16x8 ka = *(const bf16x8*)(k0p + lg * 8);
      bf16x8 kb = *(const bf16x8*)(k0p + 32 + lg * 8);
      bf16x8 kc = *(const bf16x8*)(k1p + lg * 8);
      bf16x8 kd = *(const bf16x8*)(k1p + 32 + lg * 8);
      s0 = __builtin_amdgcn_mfma_f32_16x16x32_bf16(qf0, ka, s0, 0, 0, 0);
      s0 = __builtin_amdgcn_mfma_f32_16x16x32_bf16(qf1, kb, s0, 0, 0, 0);
      s1 = __builtin_amdgcn_mfma_f32_16x16x32_bf16(qf0, kc, s1, 0, 0, 0);
      s1 = __builtin_amdgcn_mfma_f32_16x16x32_bf16(qf1, kd, s1, 0, 0, 0);
    }

    // causal mask: kv > q  -> -inf-ish
#pragma unroll
    for (int r = 0; r < 4; ++r) {
      if (kv0 + l16 > my_q + r) s0[r] = -3.0e38f;
      if (kv0 + 16 + l16 > my_q + r) s1[r] = -3.0e38f;
    }

    // row max across the 16 col-lanes (rows live in lg-group, cols in low 4 lane bits)
    f32x4 mx;
#pragma unroll
    for (int r = 0; r < 4; ++r) mx[r] = fmaxf(s0[r], s1[r]);
#pragma unroll
    for (int d = 1; d < 16; d <<= 1) {
#pragma unroll
      for (int r = 0; r < 4; ++r) mx[r] = fmaxf(mx[r], __shfl_xor(mx[r], d));
    }

    float al[4];
    f32x4 p0, p1, ps;
#pragma unroll
    for (int r = 0; r < 4; ++r) {
      float mn = fmaxf(m_[r], mx[r]);
      al[r] = exp2f((m_[r] - mn) * LOG2E);
      m_[r] = mn;
      p0[r] = exp2f((s0[r] - mn) * LOG2E);
      p1[r] = exp2f((s1[r] - mn) * LOG2E);
      ps[r] = p0[r] + p1[r];
    }
#pragma unroll
    for (int d = 1; d < 16; d <<= 1) {
#pragma unroll
      for (int r = 0; r < 4; ++r) ps[r] += __shfl_xor(ps[r], d);
    }
#pragma unroll
    for (int r = 0; r < 4; ++r) {
      lsum[r] = lsum[r] * al[r] + ps[r];
      o0[r] *= al[r]; o1[r] *= al[r]; o2[r] *= al[r]; o3[r] *= al[r];
    }

    // P (D-layout) -> LDS -> A-fragment layout
#pragma unroll
    for (int r = 0; r < 4; ++r) {
      P_lds[wid][lg * 4 + r][l16] = f2bf(p0[r]);
      P_lds[wid][lg * 4 + r][16 + l16] = f2bf(p1[r]);
    }
    asm volatile("s_waitcnt lgkmcnt(0)" ::: "memory");

    bf16x8 pf = *(const bf16x8*)(&P_lds[wid][l16][lg * 8]);
    bf16x8 v0 = *(const bf16x8*)(&V_lds[l16][lg * 8]);
    bf16x8 v1 = *(const bf16x8*)(&V_lds[16 + l16][lg * 8]);
    bf16x8 v2 = *(const bf16x8*)(&V_lds[32 + l16][lg * 8]);
    bf16x8 v3 = *(const bf16x8*)(&V_lds[48 + l16][lg * 8]);
    o0 = __builtin_amdgcn_mfma_f32_16x16x32_bf16(pf, v0, o0, 0, 0, 0);
    o1 = __builtin_amdgcn_mfma_f32_16x16x32_bf16(pf, v1, o1, 0, 0, 0);
    o2 = __builtin_amdgcn_mfma_f32_16x16x32_bf16(pf, v2, o2, 0, 0, 0);
    o3 = __builtin_amdgcn_mfma_f32_16x16x32_bf16(pf, v3, o3, 0, 0, 0);

    __syncthreads();   // protect V_lds before next stage
  }

  // epilogue: divide by lsum, store fp32
  float inv[4];
#pragma unroll
  for (int r = 0; r < 4; ++r) inv[r] = 1.0f / lsum[r];
  const size_t orow = (size_t)b * SEQ + q0 + wid * 16 + lg * 4;
#pragma unroll
  for (int r = 0; r < 4; ++r) {
    out[(orow + r) * HEAD + 0 + l16] = o0[r] * inv[r];
    out[(orow + r) * HEAD + 16 + l16] = o1[r] * inv[r];
    out[(orow + r) * HEAD + 32 + l16] = o2[r] * inv[r];
    out[(orow + r) * HEAD + 48 + l16] = o3[r] * inv[r];
  }
}

extern "C" void kernel_launch(void* const* d_in, const int* in_sizes, int n_in,
                              void* d_out, int out_size, void* d_ws, size_t ws_size,
                              hipStream_t stream) {
  (void)in_sizes; (void)n_in; (void)out_size; (void)ws_size;
  const float* x = (const float*)d_in[0];
  const float* W = (const float*)d_in[1];
  float* out = (float*)d_out;

  unsigned short* Wt = (unsigned short*)d_ws;                         // 384 KB
  unsigned short* kqv = (unsigned short*)((char*)d_ws + 512 * 1024);  // 12.6 MB

  hipLaunchKernelGGL(wt_kernel, dim3((EMB * N3) / 256), dim3(256), 0, stream, W, Wt);
  hipLaunchKernelGGL(qkv_kernel, dim3((BATCH * SEQ) / 64), dim3(256), 0, stream, x, Wt, kqv);
  hipLaunchKernelGGL(attn_kernel, dim3(BATCH * (SEQ / QBLK)), dim3(256), 0, stream, kqv, out);
}

// Round 2
// 253.084 us; speedup vs baseline: 1.5375x; 1.5375x over previous
//
#include <hip/hip_runtime.h>
#include <hip/hip_bf16.h>

#define BATCH 8
#define SEQ 4096
#define EMB 1024
#define HEAD 64
#define N3 192      // 3*HEAD: k | q | v
#define KQ_STR 128  // dense K|Q row stride

typedef __attribute__((ext_vector_type(4))) float f32x4;
typedef __attribute__((ext_vector_type(8))) short bf16x8;
typedef __attribute__((ext_vector_type(4))) float float4v;
typedef __attribute__((ext_vector_type(4))) unsigned int u32x4;

#define LOG2E 1.4426950408889634f

static __device__ __forceinline__ unsigned short f2bf(float f) {
  unsigned int x = __builtin_bit_cast(unsigned int, f);
  x += 0x7fffu + ((x >> 16) & 1u);   // RTNE
  return (unsigned short)(x >> 16);
}

// --- Kernel 1: W [1024][192] f32 -> Wt [192][1024] bf16 ---
__global__ __launch_bounds__(256) void wt_kernel(const float* __restrict__ W,
                                                 unsigned short* __restrict__ Wt) {
  int idx = blockIdx.x * 256 + threadIdx.x;
  int k = idx / N3, c = idx % N3;
  Wt[(size_t)c * EMB + k] = f2bf(W[idx]);
}

// --- Kernel 2: kq[32768][128] = [K|Q] bf16 (Q pre-scaled 0.125), Vt[B][64][4096] bf16 ---
__global__ __launch_bounds__(256) void qkv_kernel(const float* __restrict__ x,
                                                  const unsigned short* __restrict__ Wt,
                                                  unsigned short* __restrict__ kq,
                                                  unsigned short* __restrict__ Vt) {
  const int wid = threadIdx.x >> 6;
  const int lane = threadIdx.x & 63;
  const int l16 = lane & 15;
  const int lg = lane >> 4;
  const int m0 = blockIdx.x * 64 + wid * 16;

  f32x4 acc[12];
#pragma unroll
  for (int t = 0; t < 12; ++t) acc[t] = (f32x4)0.0f;

  const float* xrow = x + (size_t)(m0 + l16) * EMB;
  for (int kc = 0; kc < EMB; kc += 32) {
    float4v a0 = *(const float4v*)(xrow + kc + lg * 8);
    float4v a1 = *(const float4v*)(xrow + kc + lg * 8 + 4);
    bf16x8 af;
#pragma unroll
    for (int j = 0; j < 4; ++j) {
      af[j] = (short)f2bf(a0[j]);
      af[4 + j] = (short)f2bf(a1[j]);
    }
#pragma unroll
    for (int t = 0; t < 12; ++t) {
      bf16x8 bfv = *(const bf16x8*)(Wt + (size_t)(t * 16 + l16) * EMB + kc + lg * 8);
      acc[t] = __builtin_amdgcn_mfma_f32_16x16x32_bf16(af, bfv, acc[t], 0, 0, 0);
    }
  }
  // D layout: col = t*16+l16, row = m0 + lg*4 + r
#pragma unroll
  for (int t = 0; t < 12; ++t) {
#pragma unroll
    for (int r = 0; r < 4; ++r) {
      int row = m0 + lg * 4 + r;
      float v = acc[t][r];
      if (t >= 4 && t < 8) v *= 0.125f;   // q pre-scale 1/sqrt(64)
      unsigned short h = f2bf(v);
      if (t < 8) {
        kq[(size_t)row * KQ_STR + t * 16 + l16] = h;
      } else {
        int bb = row >> 12;
        int ss = row & (SEQ - 1);
        Vt[((size_t)bb * HEAD + (t - 8) * 16 + l16) * SEQ + ss] = h;
      }
    }
  }
}

// --- Kernel 3: causal flash attention, barrier-free, one 16-row q-chunk per wave ---
__global__ __launch_bounds__(256) void attn_kernel(const unsigned short* __restrict__ kq,
                                                   const unsigned short* __restrict__ Vt,
                                                   float* __restrict__ out) {
  const int tid = threadIdx.x;
  const int wid = tid >> 6;
  const int lane = tid & 63;
  const int l16 = lane & 15;
  const int lg = lane >> 4;

  // block B and B+256 carry complementary chunk lengths; batch = blockIdx%8 (XCD affinity)
  const int Bid = blockIdx.x;
  const int half = Bid >> 8;
  const int rr = Bid & 255;
  const int b = rr & 7;
  const int ii = rr >> 3;          // [0,32)
  int qc = 4 * ii + wid;           // [0,128)
  if (half) qc = 255 - qc;         // [128,256)
  const int q0 = qc * 16;
  const int ntiles = (q0 + 16 + 63) >> 6;

  const unsigned short* kqb = kq + (size_t)b * SEQ * KQ_STR;
  const unsigned short* vtb = Vt + (size_t)b * HEAD * SEQ;

  // Q fragments (B-operand of S^T mfma): col=l16 -> q row, k=lg*8+j -> d
  bf16x8 qf0 = *(const bf16x8*)(kqb + (size_t)(q0 + l16) * KQ_STR + 64 + lg * 8);
  bf16x8 qf1 = *(const bf16x8*)(kqb + (size_t)(q0 + l16) * KQ_STR + 96 + lg * 8);

  f32x4 o[4];
#pragma unroll
  for (int dd = 0; dd < 4; ++dd) o[dd] = (f32x4)0.0f;
  float m_ = -3.0e38f, lsum = 0.0f;

  // preload K tile 0 (A-operand: row=l16 -> kv, k=lg*8+j -> d)
  bf16x8 kf[8], kn[8];
#pragma unroll
  for (int t = 0; t < 4; ++t) {
    const unsigned short* kp = kqb + (size_t)(t * 16 + l16) * KQ_STR + lg * 8;
    kf[2 * t] = *(const bf16x8*)(kp);
    kf[2 * t + 1] = *(const bf16x8*)(kp + 32);
  }

  for (int it = 0; it < ntiles; ++it) {
    const int kv0 = it << 6;

    // prefetch next K tile (clamped; covered by this tile's compute)
    int kvn = kv0 + 64;
    if (kvn > SEQ - 64) kvn = SEQ - 64;
#pragma unroll
    for (int t = 0; t < 4; ++t) {
      const unsigned short* kp = kqb + (size_t)(kvn + t * 16 + l16) * KQ_STR + lg * 8;
      kn[2 * t] = *(const bf16x8*)(kp);
      kn[2 * t + 1] = *(const bf16x8*)(kp + 32);
    }
    // V fragments for this tile (A-operand of PV: row=l16 -> d, k -> kv)
    bf16x8 vf[8];
#pragma unroll
    for (int dd = 0; dd < 4; ++dd) {
      const unsigned short* vp = vtb + (size_t)(dd * 16 + l16) * SEQ + kv0 + lg * 8;
      vf[2 * dd] = *(const bf16x8*)(vp);
      vf[2 * dd + 1] = *(const bf16x8*)(vp + 32);
    }

    // S^T[kv][q]: lane holds kv = kv0+16t+lg*4+r for q = q0+l16
    f32x4 s[4];
#pragma unroll
    for (int t = 0; t < 4; ++t) {
      f32x4 z = (f32x4)0.0f;
      z = __builtin_amdgcn_mfma_f32_16x16x32_bf16(kf[2 * t], qf0, z, 0, 0, 0);
      z = __builtin_amdgcn_mfma_f32_16x16x32_bf16(kf[2 * t + 1], qf1, z, 0, 0, 0);
      s[t] = z;
    }

    // causal mask only on diagonal-crossing tiles (uniform branch)
    if (kv0 + 64 > q0) {
      const int base = kv0 + lg * 4 - q0 - l16;   // masked iff base + 16t + r > 0
#pragma unroll
      for (int t = 0; t < 4; ++t)
#pragma unroll
        for (int r = 0; r < 4; ++r)
          if (base + 16 * t + r > 0) s[t][r] = -3.0e38f;
    }

    // row max: 15 in-lane fmax + 2 shfl (across lg groups)
    float mx = s[0][0];
#pragma unroll
    for (int t = 0; t < 4; ++t)
#pragma unroll
      for (int r = 0; r < 4; ++r)
        mx = fmaxf(mx, s[t][r]);
    mx = fmaxf(mx, __shfl_xor(mx, 16));
    mx = fmaxf(mx, __shfl_xor(mx, 32));

    // defer-max: rescale only when some row's max grew
    if (!__all(mx <= m_)) {
      float mn = fmaxf(m_, mx);
      float al = exp2f((m_ - mn) * LOG2E);
      m_ = mn;
      lsum *= al;
#pragma unroll
      for (int dd = 0; dd < 4; ++dd) o[dd] *= al;
    }

    // P = exp(S - m), pack to bf16 pairs, row-sum
    unsigned int pk[8];
    float ps = 0.0f;
#pragma unroll
    for (int t = 0; t < 4; ++t) {
      float p0 = exp2f((s[t][0] - m_) * LOG2E);
      float p1 = exp2f((s[t][1] - m_) * LOG2E);
      float p2 = exp2f((s[t][2] - m_) * LOG2E);
      float p3 = exp2f((s[t][3] - m_) * LOG2E);
      ps += (p0 + p1) + (p2 + p3);
      pk[2 * t] = (unsigned int)f2bf(p0) | ((unsigned int)f2bf(p1) << 16);
      pk[2 * t + 1] = (unsigned int)f2bf(p2) | ((unsigned int)f2bf(p3) << 16);
    }
    ps += __shfl_xor(ps, 16);
    ps += __shfl_xor(ps, 32);
    lsum += ps;

    // permute P into B-fragment layout: lane needs P[q=l16][kv=32c+lg*8+j]
    const int srcA = l16 + ((lg & 1) << 5);
    const int srcB = srcA + 16;
    const int hi = lg >> 1;
#pragma unroll
    for (int c = 0; c < 2; ++c) {
      unsigned int d0a = (unsigned int)__shfl((int)pk[4 * c], srcA);
      unsigned int d0b = (unsigned int)__shfl((int)pk[4 * c + 2], srcA);
      unsigned int d1a = (unsigned int)__shfl((int)pk[4 * c + 1], srcA);
      unsigned int d1b = (unsigned int)__shfl((int)pk[4 * c + 3], srcA);
      unsigned int d2a = (unsigned int)__shfl((int)pk[4 * c], srcB);
      unsigned int d2b = (unsigned int)__shfl((int)pk[4 * c + 2], srcB);
      unsigned int d3a = (unsigned int)__shfl((int)pk[4 * c + 1], srcB);
      unsigned int d3b = (unsigned int)__shfl((int)pk[4 * c + 3], srcB);
      u32x4 pw;
      pw[0] = hi ? d0b : d0a;
      pw[1] = hi ? d1b : d1a;
      pw[2] = hi ? d2b : d2a;
      pw[3] = hi ? d3b : d3a;
      bf16x8 pf = __builtin_bit_cast(bf16x8, pw);
#pragma unroll
      for (int dd = 0; dd < 4; ++dd)
        o[dd] = __builtin_amdgcn_mfma_f32_16x16x32_bf16(vf[2 * dd + c], pf, o[dd], 0, 0, 0);
    }

#pragma unroll
    for (int j = 0; j < 8; ++j) kf[j] = kn[j];
  }

  // epilogue: O^T in regs -> out[b][q][d], q = q0+l16, d = 16dd + lg*4 + r
  const float inv = 1.0f / lsum;
  float* op = out + ((size_t)b * SEQ + q0 + l16) * HEAD;
#pragma unroll
  for (int dd = 0; dd < 4; ++dd)
#pragma unroll
    for (int r = 0; r < 4; ++r)
      op[16 * dd + lg * 4 + r] = o[dd][r] * inv;
}

extern "C" void kernel_launch(void* const* d_in, const int* in_sizes, int n_in,
                              void* d_out, int out_size, void* d_ws, size_t ws_size,
                              hipStream_t stream) {
  (void)in_sizes; (void)n_in; (void)out_size; (void)ws_size;
  const float* x = (const float*)d_in[0];
  const float* W = (const float*)d_in[1];
  float* out = (float*)d_out;

  unsigned short* Wt = (unsigned short*)d_ws;                                   // 384 KB
  unsigned short* kq = (unsigned short*)((char*)d_ws + 512 * 1024);             // 8 MB
  unsigned short* Vt = (unsigned short*)((char*)d_ws + 512 * 1024 + (size_t)BATCH * SEQ * KQ_STR * 2);  // 4 MB

  hipLaunchKernelGGL(wt_kernel, dim3((EMB * N3) / 256), dim3(256), 0, stream, W, Wt);
  hipLaunchKernelGGL(qkv_kernel, dim3((BATCH * SEQ) / 64), dim3(256), 0, stream, x, Wt, kq, Vt);
  hipLaunchKernelGGL(attn_kernel, dim3(2 * BATCH * 32), dim3(256), 0, stream, kq, Vt, out);
}